// Round 4
// baseline (134.560 us; speedup 1.0000x reference)
//
#include <hip/hip_runtime.h>

// LogicGatedSNN fused kernel, v3: one wave per output row, zero barriers.
// Outputs concatenated in d_out (all float32):
//   [0, 8192)                 spikes
//   [8192, 16384)             new_v_mem
//   [16384, 16384+8192*8192)  new_trace (row-major [out][in])

#define IN_F 8192
#define OUT_F 8192
#define THR_F 50.0f
#define BLOCK 256          // 4 waves -> 4 rows per block
#define WAVES_PER_BLOCK 4
// per row: 8192/4 = 2048 f4; per lane: 2048/64 = 32 f4; 4 chunks of 8
#define CHUNK 8
#define NCHUNK 4

typedef float f4 __attribute__((ext_vector_type(4)));

__global__ __launch_bounds__(BLOCK) void snn_wave_kernel(
    const float* __restrict__ x,        // [IN_F]
    const float* __restrict__ syn,      // [OUT_F * IN_F]
    const float* __restrict__ vmem_in,  // [OUT_F]
    const float* __restrict__ thr,      // [OUT_F]
    const float* __restrict__ trace_in, // [OUT_F * IN_F]
    float* __restrict__ out_spikes,     // [OUT_F]
    float* __restrict__ out_vmem,       // [OUT_F]
    float* __restrict__ out_trace)      // [OUT_F * IN_F]
{
    const int wid  = threadIdx.x >> 6;
    const int lane = threadIdx.x & 63;
    const int o    = blockIdx.x * WAVES_PER_BLOCK + wid;
    const size_t rowoff = (size_t)o * IN_F;

    const f4* __restrict__ syn4 = reinterpret_cast<const f4*>(syn + rowoff);
    const f4* __restrict__ x4   = reinterpret_cast<const f4*>(x);
    const f4* __restrict__ tr4  = reinterpret_cast<const f4*>(trace_in + rowoff);
    f4* __restrict__ ot4        = reinterpret_cast<f4*>(out_trace + rowoff);

    // ---- Phase 1: row dot, streamed in 4 chunks of 8 f4 per lane ----
    float partial = 0.0f;
#pragma unroll
    for (int c = 0; c < NCHUNK; ++c) {
        f4 s[CHUNK], xv[CHUNK];
#pragma unroll
        for (int j = 0; j < CHUNK; ++j) {
            const int idx = lane + (c * CHUNK + j) * 64;
            s[j]  = __builtin_nontemporal_load(&syn4[idx]);
            xv[j] = x4[idx];
        }
#pragma unroll
        for (int j = 0; j < CHUNK; ++j) {
            partial += (s[j].x > THR_F) ? xv[j].x : 0.0f;
            partial += (s[j].y > THR_F) ? xv[j].y : 0.0f;
            partial += (s[j].z > THR_F) ? xv[j].z : 0.0f;
            partial += (s[j].w > THR_F) ? xv[j].w : 0.0f;
        }
    }

    // ---- Prefetch first trace chunk; its latency hides under the reduce ----
    f4 tpre[CHUNK];
#pragma unroll
    for (int j = 0; j < CHUNK; ++j)
        tpre[j] = __builtin_nontemporal_load(&tr4[lane + j * 64]);

    // ---- Wave-64 butterfly reduce (register-only, no LDS) ----
#pragma unroll
    for (int off = 32; off > 0; off >>= 1)
        partial += __shfl_xor(partial, off, 64);

    // ---- LIF update on lane 0, broadcast spike ----
    float sp;
    if (lane == 0) {
        const float v = vmem_in[o] * 0.7f + partial;
        sp = (v >= thr[o]) ? 1.0f : 0.0f;
        out_spikes[o] = sp;
        out_vmem[o]   = v * (1.0f - sp) * 0.5f;
    }
    sp = __shfl(sp, 0, 64);

    // ---- Phase 2: trace update, chunk 0 from prefetch ----
#pragma unroll
    for (int j = 0; j < CHUNK; ++j) {
        const int idx = lane + j * 64;
        const f4 xv = x4[idx];
        f4 r;
        r.x = tpre[j].x * 0.8f + sp * xv.x;
        r.y = tpre[j].y * 0.8f + sp * xv.y;
        r.z = tpre[j].z * 0.8f + sp * xv.z;
        r.w = tpre[j].w * 0.8f + sp * xv.w;
        __builtin_nontemporal_store(r, &ot4[idx]);
    }
#pragma unroll
    for (int c = 1; c < NCHUNK; ++c) {
        f4 t[CHUNK], xv[CHUNK];
#pragma unroll
        for (int j = 0; j < CHUNK; ++j) {
            const int idx = lane + (c * CHUNK + j) * 64;
            t[j]  = __builtin_nontemporal_load(&tr4[idx]);
            xv[j] = x4[idx];
        }
#pragma unroll
        for (int j = 0; j < CHUNK; ++j) {
            const int idx = lane + (c * CHUNK + j) * 64;
            f4 r;
            r.x = t[j].x * 0.8f + sp * xv[j].x;
            r.y = t[j].y * 0.8f + sp * xv[j].y;
            r.z = t[j].z * 0.8f + sp * xv[j].z;
            r.w = t[j].w * 0.8f + sp * xv[j].w;
            __builtin_nontemporal_store(r, &ot4[idx]);
        }
    }
}

extern "C" void kernel_launch(void* const* d_in, const int* in_sizes, int n_in,
                              void* d_out, int out_size, void* d_ws, size_t ws_size,
                              hipStream_t stream) {
    const float* x     = (const float*)d_in[0]; // spike_input [1,8192]
    const float* syn   = (const float*)d_in[1]; // synapse_states [8192,8192]
    const float* vmem  = (const float*)d_in[2]; // membrane_potential [8192]
    const float* thr   = (const float*)d_in[3]; // adaptive_threshold [8192]
    const float* trace = (const float*)d_in[4]; // eligibility_trace [8192,8192]

    float* out = (float*)d_out;
    float* out_spikes = out;             // [8192]
    float* out_vmem   = out + OUT_F;     // [8192]
    float* out_trace  = out + 2 * OUT_F; // [8192*8192]

    snn_wave_kernel<<<OUT_F / WAVES_PER_BLOCK, BLOCK, 0, stream>>>(
        x, syn, vmem, thr, trace, out_spikes, out_vmem, out_trace);
}